// Round 1
// baseline (182.907 us; speedup 1.0000x reference)
//
#include <hip/hip_runtime.h>

// RoIAlign1D: feat [B,T,D] f32, spans [B,K,2] i32, lengths [B] i32 -> out [B,K,P,D] f32
// B=16, T=4096, D=512, K=64, P=16

constexpr int B = 16;
constexpr int T = 4096;
constexpr int D = 512;
constexpr int K = 64;
constexpr int P = 16;

// One block per output row (b,k,p): 128 threads x float4 = 512 floats = D.
__global__ __launch_bounds__(128) void roialign1d_kernel(
    const float* __restrict__ feat,
    const int* __restrict__ spans,
    const int* __restrict__ lengths,
    float* __restrict__ out) {

    const int bkp = blockIdx.x;       // [0, B*K*P)
    const int p   = bkp & (P - 1);    // P = 16
    const int bk  = bkp >> 4;         // b*K + k
    const int b   = bk >> 6;          // K = 64

    const int Lm1 = lengths[b] - 1;
    int s0 = spans[bk * 2 + 0];
    int s1 = spans[bk * 2 + 1];
    s0 = min(max(s0, 0), Lm1);
    s1 = min(max(s1, 0), Lm1);
    const int s      = min(s0, s1);
    const int e      = max(s0, s1);
    const int seglen = e - s + 1;

    // Exact fp32 replication of the reference linspace math.
    const float t   = (float)p / 15.0f;            // p / (P-1)
    const float idx = t * (float)(seglen - 1);
    const int idx0  = min((int)floorf(idx), seglen - 1);
    const int idx1  = min(idx0 + 1, seglen - 1);
    const float w   = idx - (float)idx0;           // after the min, per reference

    const float4* __restrict__ f0 =
        (const float4*)(feat + ((size_t)b * T + (size_t)(s + idx0)) * D);
    const float4* __restrict__ f1 =
        (const float4*)(feat + ((size_t)b * T + (size_t)(s + idx1)) * D);
    float4* __restrict__ o = (float4*)(out + ((size_t)bk * P + p) * D);

    const int d = threadIdx.x;        // 128 float4 slots = D/4
    const float4 a = f0[d];
    const float4 c = f1[d];
    float4 r;
    const float wm = 1.0f - w;
    r.x = wm * a.x + w * c.x;
    r.y = wm * a.y + w * c.y;
    r.z = wm * a.z + w * c.z;
    r.w = wm * a.w + w * c.w;
    o[d] = r;
}

extern "C" void kernel_launch(void* const* d_in, const int* in_sizes, int n_in,
                              void* d_out, int out_size, void* d_ws, size_t ws_size,
                              hipStream_t stream) {
    const float* feat    = (const float*)d_in[0];
    const int*   spans   = (const int*)d_in[1];
    const int*   lengths = (const int*)d_in[2];
    float*       out     = (float*)d_out;

    const int n_rows = B * K * P;  // 16384 blocks
    roialign1d_kernel<<<n_rows, 128, 0, stream>>>(feat, spans, lengths, out);
}